// Round 1
// baseline (415.631 us; speedup 1.0000x reference)
//
#include <hip/hip_runtime.h>
#include <math.h>

#define NB 64    // batches
#define NN 512   // sequence length
#define NE 12    // embed dim
#define NH 4     // heads
#define ND 3     // head dim
#define NF 13    // features (F-3)

// ---------------------------------------------------------------------------
// prep: center coords, compute y_translate, project coords->E and feats->E
// grid: NB blocks, NN threads
// ---------------------------------------------------------------------------
__global__ __launch_bounds__(512) void prep_kernel(
    const float* __restrict__ x_orig, const float* __restrict__ y_orig,
    const float* __restrict__ lin_in_w, const float* __restrict__ lin_in_b,
    const float* __restrict__ lin_coords_w, const float* __restrict__ lin_coords_b,
    float* __restrict__ x_c, float* __restrict__ y_tr,
    float* __restrict__ xi, float* __restrict__ yi,
    float* __restrict__ xi_feat, float* __restrict__ yi_feat)
{
    const int b = blockIdx.x;
    const int n = threadIdx.x;
    const size_t row = (size_t)b * NN + n;
    const float* xr = x_orig + row * 16;
    const float* yr = y_orig + row * 16;
    float xv[16], yv[16];
#pragma unroll
    for (int i = 0; i < 16; ++i) { xv[i] = xr[i]; yv[i] = yr[i]; }

    __shared__ float red[512];
    float xm[3], ym[3];
#pragma unroll
    for (int c = 0; c < 3; ++c) {
        red[n] = xv[c]; __syncthreads();
        for (int s = 256; s > 0; s >>= 1) { if (n < s) red[n] += red[n + s]; __syncthreads(); }
        xm[c] = red[0] * (1.0f / NN); __syncthreads();
        red[n] = yv[c]; __syncthreads();
        for (int s = 256; s > 0; s >>= 1) { if (n < s) red[n] += red[n + s]; __syncthreads(); }
        ym[c] = red[0] * (1.0f / NN); __syncthreads();
    }

    float xc[3], yc[3];
#pragma unroll
    for (int c = 0; c < 3; ++c) { xc[c] = xv[c] - xm[c]; yc[c] = yv[c] - ym[c]; }

#pragma unroll
    for (int c = 0; c < 3; ++c) x_c[row * 3 + c] = xc[c];
    if (n < 3) y_tr[b * 3 + n] = ym[n];

    // coords projection: (3) -> (12)
#pragma unroll
    for (int e = 0; e < NE; ++e) {
        float sx = lin_coords_b[e], sy = lin_coords_b[e];
#pragma unroll
        for (int c = 0; c < 3; ++c) {
            sx += xc[c] * lin_coords_w[e * 3 + c];
            sy += yc[c] * lin_coords_w[e * 3 + c];
        }
        xi[row * NE + e] = sx;
        yi[row * NE + e] = sy;
    }
    // feature projection: (13) -> (12)
#pragma unroll
    for (int e = 0; e < NE; ++e) {
        float sx = lin_in_b[e], sy = lin_in_b[e];
#pragma unroll
        for (int f = 0; f < NF; ++f) {
            sx += xv[3 + f] * lin_in_w[e * NF + f];
            sy += yv[3 + f] * lin_in_w[e * NF + f];
        }
        xi_feat[row * NE + e] = sx;
        yi_feat[row * NE + e] = sy;
    }
}

// ---------------------------------------------------------------------------
// attention (fused QKV projection + flash-style online softmax), per (b,h)
// grid: NB*NH blocks, 256 threads; each thread handles rows tid and tid+256
// out_heads[b,n,h*3+c]
// ---------------------------------------------------------------------------
__global__ __launch_bounds__(256) void attn_kernel(
    const float* __restrict__ qin, const float* __restrict__ kvin,
    const float* __restrict__ w_in, const float* __restrict__ b_in,
    float* __restrict__ out_heads)
{
    const int b = blockIdx.x >> 2;
    const int h = blockIdx.x & 3;
    const int tid = threadIdx.x;

    __shared__ float kh[NN][3];
    __shared__ float vh[NN][3];
    __shared__ float wq[3][NE], wk[3][NE], wv[3][NE];
    __shared__ float bqkv[9]; // bq[0..2], bk[3..5], bv[6..8]

    if (tid < 36) {
        int r = tid / NE, c = tid % NE;
        wq[r][c] = w_in[(h * 3 + r) * NE + c];
        wk[r][c] = w_in[(NE + h * 3 + r) * NE + c];
        wv[r][c] = w_in[(2 * NE + h * 3 + r) * NE + c];
    }
    if (tid < 3) {
        bqkv[tid]     = b_in[h * 3 + tid];
        bqkv[3 + tid] = b_in[NE + h * 3 + tid];
        bqkv[6 + tid] = b_in[2 * NE + h * 3 + tid];
    }
    __syncthreads();

    // stage K,V heads into LDS
    for (int n = tid; n < NN; n += 256) {
        const float* kv = kvin + ((size_t)b * NN + n) * NE;
        float x[NE];
#pragma unroll
        for (int e = 0; e < NE; ++e) x[e] = kv[e];
#pragma unroll
        for (int c = 0; c < 3; ++c) {
            float sk = bqkv[3 + c], sv = bqkv[6 + c];
#pragma unroll
            for (int e = 0; e < NE; ++e) { sk += x[e] * wk[c][e]; sv += x[e] * wv[c][e]; }
            kh[n][c] = sk; vh[n][c] = sv;
        }
    }
    __syncthreads();

    // Q for two rows
    float q0[3], q1[3];
    {
        const float* qp0 = qin + ((size_t)b * NN + tid) * NE;
        const float* qp1 = qp0 + 256 * NE;
        float x0[NE], x1[NE];
#pragma unroll
        for (int e = 0; e < NE; ++e) { x0[e] = qp0[e]; x1[e] = qp1[e]; }
#pragma unroll
        for (int c = 0; c < 3; ++c) {
            float s0 = bqkv[c], s1 = bqkv[c];
#pragma unroll
            for (int e = 0; e < NE; ++e) { s0 += x0[e] * wq[c][e]; s1 += x1[e] * wq[c][e]; }
            q0[c] = s0; q1[c] = s1;
        }
    }

    const float scale = 0.57735026918962576f; // 1/sqrt(3)
    float m0 = -INFINITY, l0 = 0.f, o00 = 0.f, o01 = 0.f, o02 = 0.f;
    float m1 = -INFINITY, l1 = 0.f, o10 = 0.f, o11 = 0.f, o12 = 0.f;

    for (int k = 0; k < NN; ++k) {
        float k0 = kh[k][0], k1 = kh[k][1], k2 = kh[k][2];
        float v0 = vh[k][0], v1 = vh[k][1], v2 = vh[k][2];
        float s0 = scale * (q0[0] * k0 + q0[1] * k1 + q0[2] * k2);
        float s1 = scale * (q1[0] * k0 + q1[1] * k1 + q1[2] * k2);
        float mn0 = fmaxf(m0, s0);
        float cr0 = __expf(m0 - mn0);
        float p0  = __expf(s0 - mn0);
        l0 = l0 * cr0 + p0;
        o00 = o00 * cr0 + p0 * v0;
        o01 = o01 * cr0 + p0 * v1;
        o02 = o02 * cr0 + p0 * v2;
        m0 = mn0;
        float mn1 = fmaxf(m1, s1);
        float cr1 = __expf(m1 - mn1);
        float p1  = __expf(s1 - mn1);
        l1 = l1 * cr1 + p1;
        o10 = o10 * cr1 + p1 * v0;
        o11 = o11 * cr1 + p1 * v1;
        o12 = o12 * cr1 + p1 * v2;
        m1 = mn1;
    }
    float inv0 = 1.0f / l0, inv1 = 1.0f / l1;
    size_t r0 = ((size_t)b * NN + tid) * NE + h * 3;
    size_t r1 = r0 + (size_t)256 * NE;
    out_heads[r0 + 0] = o00 * inv0;
    out_heads[r0 + 1] = o01 * inv0;
    out_heads[r0 + 2] = o02 * inv0;
    out_heads[r1 + 0] = o10 * inv1;
    out_heads[r1 + 1] = o11 * inv1;
    out_heads[r1 + 2] = o12 * inv1;
}

// ---------------------------------------------------------------------------
// output projection: out = in @ w_out.T + b_out  (12 -> 12), one row/thread
// ---------------------------------------------------------------------------
__global__ __launch_bounds__(256) void proj_kernel(
    const float* __restrict__ in, const float* __restrict__ w,
    const float* __restrict__ bias, float* __restrict__ out)
{
    const int idx = blockIdx.x * 256 + threadIdx.x;
    if (idx >= NB * NN) return;
    const float* p = in + (size_t)idx * NE;
    float x[NE];
#pragma unroll
    for (int e = 0; e < NE; ++e) x[e] = p[e];
#pragma unroll
    for (int o = 0; o < NE; ++o) {
        float s = bias[o];
#pragma unroll
        for (int e = 0; e < NE; ++e) s += x[e] * w[o * NE + e];
        out[(size_t)idx * NE + o] = s;
    }
}

// ---------------------------------------------------------------------------
// kabsch accumulation: coords = cross @ lin_out_w.T + b ; A = coords + x_c
// per batch reduce: S_BA[9] = sum Bx[i]*A[j], S_B[3], S_A[3]
// grid: NB blocks, NN threads
// ---------------------------------------------------------------------------
__global__ __launch_bounds__(512) void kabsch_accum_kernel(
    const float* __restrict__ cross, const float* __restrict__ lin_out_w,
    const float* __restrict__ lin_out_b, const float* __restrict__ x_c,
    float* __restrict__ stats)
{
    const int b = blockIdx.x;
    const int n = threadIdx.x;
    const size_t row = (size_t)b * NN + n;
    const float* xr = cross + row * NE;
    float xin[NE];
#pragma unroll
    for (int e = 0; e < NE; ++e) xin[e] = xr[e];
    float cd[3];
#pragma unroll
    for (int o = 0; o < 3; ++o) {
        float s = lin_out_b[o];
#pragma unroll
        for (int e = 0; e < NE; ++e) s += xin[e] * lin_out_w[o * NE + e];
        cd[o] = s;
    }
    float Bx[3], A[3];
#pragma unroll
    for (int c = 0; c < 3; ++c) { Bx[c] = x_c[row * 3 + c]; A[c] = cd[c] + Bx[c]; }

    float vals[15];
#pragma unroll
    for (int i = 0; i < 3; ++i)
#pragma unroll
        for (int j = 0; j < 3; ++j) vals[i * 3 + j] = Bx[i] * A[j];
#pragma unroll
    for (int i = 0; i < 3; ++i) { vals[9 + i] = Bx[i]; vals[12 + i] = A[i]; }

    __shared__ float red[512];
    for (int t = 0; t < 15; ++t) {
        red[n] = vals[t]; __syncthreads();
        for (int s = 256; s > 0; s >>= 1) { if (n < s) red[n] += red[n + s]; __syncthreads(); }
        if (n == 0) stats[b * 15 + t] = red[0];
        __syncthreads();
    }
}

// ---------------------------------------------------------------------------
// kabsch R: polar factor of H via det-scaled Newton; t = cA - cB @ R
// one block of 64 threads, thread = batch
// ---------------------------------------------------------------------------
__global__ __launch_bounds__(64) void kabsch_r_kernel(
    const float* __restrict__ stats, float* __restrict__ Rb, float* __restrict__ tb)
{
    const int b = threadIdx.x;
    if (b >= NB) return;
    const float* s = stats + b * 15;
    float cB[3], cA[3];
#pragma unroll
    for (int j = 0; j < 3; ++j) { cB[j] = s[9 + j] * (1.0f / NN); cA[j] = s[12 + j] * (1.0f / NN); }
    float X[3][3];
#pragma unroll
    for (int i = 0; i < 3; ++i)
#pragma unroll
        for (int j = 0; j < 3; ++j) X[i][j] = s[i * 3 + j] - s[9 + i] * cA[j];

    for (int it = 0; it < 14; ++it) {
        float c00 =  X[1][1] * X[2][2] - X[1][2] * X[2][1];
        float c01 = -(X[1][0] * X[2][2] - X[1][2] * X[2][0]);
        float c02 =  X[1][0] * X[2][1] - X[1][1] * X[2][0];
        float c10 = -(X[0][1] * X[2][2] - X[0][2] * X[2][1]);
        float c11 =  X[0][0] * X[2][2] - X[0][2] * X[2][0];
        float c12 = -(X[0][0] * X[2][1] - X[0][1] * X[2][0]);
        float c20 =  X[0][1] * X[1][2] - X[0][2] * X[1][1];
        float c21 = -(X[0][0] * X[1][2] - X[0][2] * X[1][0]);
        float c22 =  X[0][0] * X[1][1] - X[0][1] * X[1][0];
        float det = X[0][0] * c00 + X[0][1] * c01 + X[0][2] * c02;
        float ad = fabsf(det);
        float g  = (ad > 1e-30f) ? 1.0f / cbrtf(ad) : 1.0f;
        float hg  = 0.5f * g;
        float hgi = 0.5f / (g * det);
        float Xn[3][3];
        Xn[0][0] = hg * X[0][0] + hgi * c00;
        Xn[0][1] = hg * X[0][1] + hgi * c01;
        Xn[0][2] = hg * X[0][2] + hgi * c02;
        Xn[1][0] = hg * X[1][0] + hgi * c10;
        Xn[1][1] = hg * X[1][1] + hgi * c11;
        Xn[1][2] = hg * X[1][2] + hgi * c12;
        Xn[2][0] = hg * X[2][0] + hgi * c20;
        Xn[2][1] = hg * X[2][1] + hgi * c21;
        Xn[2][2] = hg * X[2][2] + hgi * c22;
#pragma unroll
        for (int i = 0; i < 3; ++i)
#pragma unroll
            for (int j = 0; j < 3; ++j) X[i][j] = Xn[i][j];
    }
#pragma unroll
    for (int i = 0; i < 3; ++i)
#pragma unroll
        for (int j = 0; j < 3; ++j) Rb[b * 9 + i * 3 + j] = X[i][j];
#pragma unroll
    for (int j = 0; j < 3; ++j)
        tb[b * 3 + j] = cA[j] - (cB[0] * X[0][j] + cB[1] * X[1][j] + cB[2] * X[2][j]);
}

// ---------------------------------------------------------------------------
// final: out = x_c @ R + t + y_translate
// ---------------------------------------------------------------------------
__global__ __launch_bounds__(256) void final_kernel(
    const float* __restrict__ x_c, const float* __restrict__ Rb,
    const float* __restrict__ tb, const float* __restrict__ y_tr,
    float* __restrict__ out)
{
    const int row = blockIdx.x * 256 + threadIdx.x;
    if (row >= NB * NN) return;
    const int b = row >> 9;
    const float* R = Rb + b * 9;
    const float* t = tb + b * 3;
    const float* yt = y_tr + b * 3;
    float x0 = x_c[(size_t)row * 3 + 0];
    float x1 = x_c[(size_t)row * 3 + 1];
    float x2 = x_c[(size_t)row * 3 + 2];
#pragma unroll
    for (int j = 0; j < 3; ++j) {
        out[(size_t)row * 3 + j] = x0 * R[j] + x1 * R[3 + j] + x2 * R[6 + j] + t[j] + yt[j];
    }
}

// ---------------------------------------------------------------------------
extern "C" void kernel_launch(void* const* d_in, const int* in_sizes, int n_in,
                              void* d_out, int out_size, void* d_ws, size_t ws_size,
                              hipStream_t stream)
{
    const float* x_orig       = (const float*)d_in[0];
    const float* y_orig       = (const float*)d_in[1];
    const float* lin_in_w     = (const float*)d_in[2];
    const float* lin_in_b     = (const float*)d_in[3];
    const float* lin_coords_w = (const float*)d_in[4];
    const float* lin_coords_b = (const float*)d_in[5];
    const float* attn_w_in    = (const float*)d_in[6];
    const float* attn_b_in    = (const float*)d_in[7];
    const float* attn_w_out   = (const float*)d_in[8];
    const float* attn_b_out   = (const float*)d_in[9];
    const float* af_w_in      = (const float*)d_in[10];
    const float* af_b_in      = (const float*)d_in[11];
    const float* af_w_out     = (const float*)d_in[12];
    const float* af_b_out     = (const float*)d_in[13];
    const float* ccf_w_in     = (const float*)d_in[14];
    const float* ccf_b_in     = (const float*)d_in[15];
    const float* ccf_w_out    = (const float*)d_in[16];
    const float* ccf_b_out    = (const float*)d_in[17];
    const float* cr_w_in      = (const float*)d_in[18];
    const float* cr_b_in      = (const float*)d_in[19];
    const float* cr_w_out     = (const float*)d_in[20];
    const float* cr_b_out     = (const float*)d_in[21];
    const float* lin_out_w    = (const float*)d_in[22];
    const float* lin_out_b    = (const float*)d_in[23];

    float* ws = (float*)d_ws;
    const size_t BN3 = (size_t)NB * NN * 3;   // 98304
    const size_t BNE = (size_t)NB * NN * NE;  // 393216
    float* x_c   = ws;                 // BN3
    float* y_tr  = x_c + BN3;          // 192
    float* xi    = y_tr + 192;         // BNE
    float* yi    = xi + BNE;           // BNE
    float* xi_f  = yi + BNE;           // BNE
    float* yi_f  = xi_f + BNE;         // BNE
    float* heads = yi_f + BNE;         // BNE
    float* stats = heads + BNE;        // 64*15
    float* Rb    = stats + NB * 15;    // 64*9
    float* tb    = Rb + NB * 9;        // 64*3

    prep_kernel<<<NB, 512, 0, stream>>>(x_orig, y_orig, lin_in_w, lin_in_b,
                                        lin_coords_w, lin_coords_b,
                                        x_c, y_tr, xi, yi, xi_f, yi_f);

    auto mha = [&](const float* q, const float* kv,
                   const float* w_in, const float* b_in,
                   const float* w_out, const float* b_out, float* outp) {
        attn_kernel<<<NB * NH, 256, 0, stream>>>(q, kv, w_in, b_in, heads);
        proj_kernel<<<(NB * NN) / 256, 256, 0, stream>>>(heads, w_out, b_out, outp);
    };

    // 1. xi_feat = mha(xi_feat, self, attn_feat)
    mha(xi_f, xi_f, af_w_in, af_b_in, af_w_out, af_b_out, xi_f);
    // 2. yi_feat = mha(yi_feat, self, attn_feat)
    mha(yi_f, yi_f, af_w_in, af_b_in, af_w_out, af_b_out, yi_f);
    // 3. xi = mha(xi, self, attn)
    mha(xi, xi, attn_w_in, attn_b_in, attn_w_out, attn_b_out, xi);
    // 4. yi = mha(yi, self, attn)
    mha(yi, yi, attn_w_in, attn_b_in, attn_w_out, attn_b_out, yi);
    // 5. cross_x = mha(q=xi, kv=xi_feat, cross_cf) -> reuse xi_f slot
    mha(xi, xi_f, ccf_w_in, ccf_b_in, ccf_w_out, ccf_b_out, xi_f);
    // 6. cross_y = mha(q=yi, kv=yi_feat, cross_cf) -> reuse yi_f slot
    mha(yi, yi_f, ccf_w_in, ccf_b_in, ccf_w_out, ccf_b_out, yi_f);
    // 7. cross = mha(q=cross_x, kv=cross_y, cross) -> reuse xi slot
    mha(xi_f, yi_f, cr_w_in, cr_b_in, cr_w_out, cr_b_out, xi);

    kabsch_accum_kernel<<<NB, 512, 0, stream>>>(xi, lin_out_w, lin_out_b, x_c, stats);
    kabsch_r_kernel<<<1, 64, 0, stream>>>(stats, Rb, tb);
    final_kernel<<<(NB * NN) / 256, 256, 0, stream>>>(x_c, Rb, tb, y_tr, (float*)d_out);
}